// Round 3
// baseline (262.360 us; speedup 1.0000x reference)
//
#include <hip/hip_runtime.h>
#include <math.h>

// ProGAT: B=8,S=512,NB=23,INIT=512,E=256,R=3,T=2
// R3: fat dispatches (independent kernels in one launch), double-buffered
// MFMA GEMM (64x64 tile, XOR-swizzled LDS), 2-slice seqattn PV.

#define BSZ   8
#define SEQ   512
#define NBR   23
#define EMB   256
#define INITD 512
#define BS    (BSZ*SEQ)     // 4096
#define G3    (3*EMB)       // 768
#define NEGV  -9e8f

typedef __attribute__((ext_vector_type(8))) short short8;
typedef __attribute__((ext_vector_type(4))) float f32x4;

__device__ __forceinline__ float lrelu(float x){ return x > 0.f ? x : 0.01f*x; }
__device__ __forceinline__ float elu1 (float x){ return x > 0.f ? x : (expf(x)-1.f); }
__device__ __forceinline__ float sigm (float x){ return 1.f/(1.f+expf(-x)); }
__device__ __forceinline__ float bf2f(ushort u){
    union { unsigned int i; float f; } v; v.i = ((unsigned int)u) << 16; return v.f;
}
__device__ __forceinline__ ushort f2bf(float f){
    union { float f; unsigned int i; } v; v.f = f;
    unsigned int u = v.i;
    return (ushort)((u + 0x7FFFu + ((u >> 16) & 1u)) >> 16);   // RNE
}

struct GemmLds { ushort A[2][64][64]; ushort W[2][64][64]; };  // 32 KiB

// ---- fp32 -> bf16 converter, 7 segments in one dispatch (blockIdx.y = seg)
__global__ __launch_bounds__(256) void convert7_kernel(
    const float* s0, ushort* d0, int n0,
    const float* s1, ushort* d1, int n1,
    const float* s2, ushort* d2, int n2,
    const float* s3, ushort* d3, int n3,
    const float* s4, ushort* d4, int n4,
    const float* s5, ushort* d5, int n5,
    const float* s6, ushort* d6, int n6)
{
    const float* srcs[7] = {s0,s1,s2,s3,s4,s5,s6};
    ushort* dsts[7] = {d0,d1,d2,d3,d4,d5,d6};
    int ns[7] = {n0,n1,n2,n3,n4,n5,n6};
    int seg = blockIdx.y;
    const float* s = srcs[seg]; ushort* d = dsts[seg]; int n = ns[seg];
    size_t i = ((size_t)blockIdx.x * 256 + threadIdx.x) * 8;
    size_t stride = (size_t)gridDim.x * 256 * 8;
    for (; i < (size_t)n; i += stride) {
        float4 a = *reinterpret_cast<const float4*>(s + i);
        float4 b = *reinterpret_cast<const float4*>(s + i + 4);
        uint4 o;
        o.x = (unsigned)f2bf(a.x) | ((unsigned)f2bf(a.y) << 16);
        o.y = (unsigned)f2bf(a.z) | ((unsigned)f2bf(a.w) << 16);
        o.z = (unsigned)f2bf(b.x) | ((unsigned)f2bf(b.y) << 16);
        o.w = (unsigned)f2bf(b.z) | ((unsigned)f2bf(b.w) << 16);
        *reinterpret_cast<uint4*>(d + i) = o;
    }
}

// ---- C = act(A @ W^T + bias); MFMA 16x16x32 bf16, 64x64 tile, 4 waves,
// BK=64 double-buffered (loads for k0+64 issued before compute of k0).
template<int ACT, bool WF32, bool WBF>
__device__ __forceinline__ void gemm_dev(
    const ushort* __restrict__ A, const ushort* __restrict__ W,
    const float* __restrict__ bias,
    float* __restrict__ C, ushort* __restrict__ Cbf,
    int N, int K, int bx, int by, GemmLds& L)
{
    const int tid = threadIdx.x;
    const int m0 = bx * 64, n0 = by * 64;
    const int wv = tid >> 6, lane = tid & 63;
    const int fr = lane & 15, grp = lane >> 4;
    const int lrow = tid >> 3, lc8 = tid & 7;   // staging: 8 lanes/row, 128B/row
    const int kc = K >> 3;                       // row stride in 16B chunks
    const int sw = lc8 ^ (lrow & 7);             // XOR bank swizzle (T2)

    f32x4 acc[4];
    #pragma unroll
    for (int c = 0; c < 4; ++c) acc[c] = (f32x4){0.f, 0.f, 0.f, 0.f};

    const float4* A4 = reinterpret_cast<const float4*>(A);
    const float4* W4 = reinterpret_cast<const float4*>(W);

    // prologue: stage k0=0 into buffer 0
    float4 a0 = A4[(size_t)(m0 + lrow)      * kc + lc8];
    float4 a1 = A4[(size_t)(m0 + lrow + 32) * kc + lc8];
    float4 w0 = W4[(size_t)(n0 + lrow)      * kc + lc8];
    float4 w1 = W4[(size_t)(n0 + lrow + 32) * kc + lc8];
    *reinterpret_cast<float4*>(&L.A[0][lrow     ][sw << 3]) = a0;
    *reinterpret_cast<float4*>(&L.A[0][lrow + 32][sw << 3]) = a1;
    *reinterpret_cast<float4*>(&L.W[0][lrow     ][sw << 3]) = w0;
    *reinterpret_cast<float4*>(&L.W[0][lrow + 32][sw << 3]) = w1;
    __syncthreads();

    const int ar = (wv << 4) + fr;
    int cur = 0;
    for (int k0 = 64; k0 < K; k0 += 64) {
        // issue next-tile loads (consumed after compute -> latency hidden)
        a0 = A4[(size_t)(m0 + lrow)      * kc + (k0 >> 3) + lc8];
        a1 = A4[(size_t)(m0 + lrow + 32) * kc + (k0 >> 3) + lc8];
        w0 = W4[(size_t)(n0 + lrow)      * kc + (k0 >> 3) + lc8];
        w1 = W4[(size_t)(n0 + lrow + 32) * kc + (k0 >> 3) + lc8];
        #pragma unroll
        for (int ks = 0; ks < 2; ++ks) {
            short8 af = *reinterpret_cast<const short8*>(
                &L.A[cur][ar][((((ks << 2) + grp) ^ (ar & 7)) << 3)]);
            #pragma unroll
            for (int c = 0; c < 4; ++c) {
                const int br = (c << 4) + fr;
                short8 bv = *reinterpret_cast<const short8*>(
                    &L.W[cur][br][((((ks << 2) + grp) ^ (br & 7)) << 3)]);
                acc[c] = __builtin_amdgcn_mfma_f32_16x16x32_bf16(af, bv, acc[c], 0, 0, 0);
            }
        }
        // write next buffer (nobody reads it until the barrier)
        *reinterpret_cast<float4*>(&L.A[cur^1][lrow     ][sw << 3]) = a0;
        *reinterpret_cast<float4*>(&L.A[cur^1][lrow + 32][sw << 3]) = a1;
        *reinterpret_cast<float4*>(&L.W[cur^1][lrow     ][sw << 3]) = w0;
        *reinterpret_cast<float4*>(&L.W[cur^1][lrow + 32][sw << 3]) = w1;
        __syncthreads();
        cur ^= 1;
    }
    // final tile
    #pragma unroll
    for (int ks = 0; ks < 2; ++ks) {
        short8 af = *reinterpret_cast<const short8*>(
            &L.A[cur][ar][((((ks << 2) + grp) ^ (ar & 7)) << 3)]);
        #pragma unroll
        for (int c = 0; c < 4; ++c) {
            const int br = (c << 4) + fr;
            short8 bv = *reinterpret_cast<const short8*>(
                &L.W[cur][br][((((ks << 2) + grp) ^ (br & 7)) << 3)]);
            acc[c] = __builtin_amdgcn_mfma_f32_16x16x32_bf16(af, bv, acc[c], 0, 0, 0);
        }
    }

    // D layout (m89-verified): col = lane&15, row = (lane>>4)*4 + j
    const int mrow = m0 + (wv << 4) + (grp << 2);
    #pragma unroll
    for (int c = 0; c < 4; ++c) {
        const int n = n0 + (c << 4) + fr;
        const float bv = bias[n];
        #pragma unroll
        for (int j = 0; j < 4; ++j) {
            float t = acc[c][j] + bv;
            if (ACT == 1) t = lrelu(t);
            size_t off = (size_t)(mrow + j) * N + n;
            if (WF32) C[off] = t;
            if (WBF)  Cbf[off] = f2bf(t);
        }
    }
}

template<int ACT, bool WF32, bool WBF>
__global__ __launch_bounds__(256) void gemm_mfma(
    const ushort* __restrict__ A, const ushort* __restrict__ W,
    const float* __restrict__ bias,
    float* __restrict__ C, ushort* __restrict__ Cbf, int N, int K)
{
    __shared__ GemmLds L;
    gemm_dev<ACT,WF32,WBF>(A, W, bias, C, Cbf, N, K, blockIdx.x, blockIdx.y, L);
}

// ---- fat: feat GEMM (blocks 0..255) + nbase GEMM (256..511), K=512
__global__ __launch_bounds__(256) void featnbase_kernel(
    const ushort* __restrict__ aminobf,
    const ushort* __restrict__ embWbf, const float* __restrict__ embB,
    float* __restrict__ feat, ushort* __restrict__ featbf,
    const ushort* __restrict__ nbWbf, const float* __restrict__ nbB,
    float* __restrict__ nbase, ushort* __restrict__ nbasebf)
{
    __shared__ GemmLds L;
    int blk = blockIdx.x;
    if (blk < 256)
        gemm_dev<1,true,true>(aminobf, embWbf, embB, feat, featbf, EMB, INITD, blk & 63, blk >> 6, L);
    else {
        blk -= 256;
        gemm_dev<1,true,true>(aminobf, nbWbf, nbB, nbase, nbasebf, EMB, INITD, blk & 63, blk >> 6, L);
    }
}

// ---- fat per round: nt GEMM (0..255) + gh GEMM (256..1023) + dot2 (1024..1279)
__global__ __launch_bounds__(256) void round_pre_kernel(
    const ushort* __restrict__ nbrbf, const ushort* __restrict__ attWd,
    const float* __restrict__ attBd, ushort* __restrict__ ntb,
    const ushort* __restrict__ hprevbf, const ushort* __restrict__ gwhhd,
    const float* __restrict__ gbhhd, float* __restrict__ gh,
    const float* __restrict__ center, const float* __restrict__ nbrbase,
    const float* __restrict__ alignWd,
    float* __restrict__ cdot, float* __restrict__ ndot)
{
    __shared__ GemmLds L;
    int blk = blockIdx.x;
    if (blk < 256) {
        gemm_dev<0,false,true>(nbrbf, attWd, attBd, nullptr, ntb, EMB, EMB, blk & 63, blk >> 6, L);
    } else if (blk < 1024) {
        int b = blk - 256;
        gemm_dev<0,true,false>(hprevbf, gwhhd, gbhhd, gh, nullptr, G3, EMB, b & 63, b >> 6, L);
    } else {
        const int b    = blk - 1024;
        const int lane = threadIdx.x & 63;
        const int wv   = threadIdx.x >> 6;
        const int e    = lane << 2;
        const int rb   = b * 16 + wv * 4;
        float4 w0 = *reinterpret_cast<const float4*>(&alignWd[e]);
        float4 w1 = *reinterpret_cast<const float4*>(&alignWd[EMB + e]);
        #pragma unroll
        for (int i = 0; i < 4; ++i) {
            const int r = rb + i;
            float4 xc = *reinterpret_cast<const float4*>(&center[(size_t)r*EMB + e]);
            float4 xn = *reinterpret_cast<const float4*>(&nbrbase[(size_t)r*EMB + e]);
            float ac = xc.x*w0.x + xc.y*w0.y + xc.z*w0.z + xc.w*w0.w;
            float an = xn.x*w1.x + xn.y*w1.y + xn.z*w1.z + xn.w*w1.w;
            #pragma unroll
            for (int off = 32; off; off >>= 1) {
                ac += __shfl_xor(ac, off, 64);
                an += __shfl_xor(an, off, 64);
            }
            if (lane == 0) { cdot[r] = ac; ndot[r] = an; }
        }
    }
}

// Per row r: neighbor softmax over NB, ctxbf[r] = bf16(elu(sum_n w_n * nt[row_n])).
__global__ __launch_bounds__(256) void attn_kernel(
    const float* __restrict__ cdot, const float* __restrict__ ndot,
    const int* __restrict__ idx, const ushort* __restrict__ nt,
    const float* __restrict__ alignB, ushort* __restrict__ ctxbf)
{
    const int r   = blockIdx.x;
    const int b   = r >> 9;
    const int tid = threadIdx.x;
    __shared__ float w_s[NBR];
    __shared__ float vm_s[NBR];
    __shared__ int   row_s[NBR];
    __shared__ float red[2];
    if (tid < NBR) {
        int j = idx[(size_t)r*NBR + tid];
        int valid = (j >= 0);
        int jj = valid ? j : j + SEQ;       // JAX wrap: f[-1] = last row
        int row = b*SEQ + jj;
        row_s[tid] = row;
        vm_s[tid]  = (float)valid;
        float sc = lrelu(cdot[r] + ndot[row] + alignB[0]);
        w_s[tid] = sc + (valid ? 0.f : NEGV);
    }
    __syncthreads();
    if (tid == 0) {
        float m = w_s[0];
        for (int n = 1; n < NBR; ++n) m = fmaxf(m, w_s[n]);
        red[0] = m;
    }
    __syncthreads();
    if (tid < NBR) w_s[tid] = expf(w_s[tid] - red[0]);
    __syncthreads();
    if (tid == 0) {
        float s = 0.f;
        for (int n = 0; n < NBR; ++n) s += w_s[n];
        red[1] = 1.f / s;
    }
    __syncthreads();
    if (tid < NBR) w_s[tid] *= red[1] * vm_s[tid];
    __syncthreads();
    float acc = 0.f;
    #pragma unroll 1
    for (int n = 0; n < NBR; ++n)
        acc += w_s[n] * bf2f(nt[(size_t)row_s[n]*EMB + tid]);
    ctxbf[(size_t)r*EMB + tid] = f2bf(elu1(acc));
}

// h' = GRU(gi, gh, hprev); writes h (f32+bf16) and act=relu(h') (f32+bf16)
__global__ __launch_bounds__(256) void gru_kernel(
    const float* __restrict__ gi, const float* __restrict__ gh,
    const float* __restrict__ hprev,
    float* __restrict__ hout, ushort* __restrict__ hbf,
    float* __restrict__ actout, ushort* __restrict__ actbf)
{
    const size_t r = blockIdx.x;
    const int    e = threadIdx.x;
    float ir = gi[r*G3 + e], iz = gi[r*G3 + EMB + e], in_ = gi[r*G3 + 2*EMB + e];
    float hr = gh[r*G3 + e], hz = gh[r*G3 + EMB + e], hn  = gh[r*G3 + 2*EMB + e];
    float rg = sigm(ir + hr);
    float z  = sigm(iz + hz);
    float n  = tanhf(in_ + rg*hn);
    float hp = hprev[r*EMB + e];
    float hv = (1.f - z)*n + z*hp;
    float av = fmaxf(hv, 0.f);
    hout[r*EMB + e]   = hv;
    hbf[r*EMB + e]    = f2bf(hv);
    actout[r*EMB + e] = av;
    actbf[r*EMB + e]  = f2bf(av);
}

// ---- fat: tf GEMM (0..255) + seqsum (256..263)
__global__ __launch_bounds__(256) void seqpre_kernel(
    const ushort* __restrict__ actbf, const ushort* __restrict__ satWbf,
    const float* __restrict__ satB, float* __restrict__ tf,
    const float* __restrict__ act, const float* __restrict__ mask,
    const float* __restrict__ saW,
    float* __restrict__ seqfeat, float* __restrict__ cmol)
{
    __shared__ GemmLds L;
    int blk = blockIdx.x;
    if (blk < 256) {
        gemm_dev<0,true,false>(actbf, satWbf, satB, tf, nullptr, EMB, EMB, blk & 63, blk >> 6, L);
    } else {
        const int b = blk - 256;
        const int e = threadIdx.x;
        float acc = 0.f;
        for (int s = 0; s < SEQ; ++s)
            acc += act[((size_t)b*SEQ + s)*EMB + e] * mask[b*SEQ + s];
        seqfeat[b*EMB + e] = acc;
        float* red = reinterpret_cast<float*>(&L);
        red[e] = fmaxf(acc, 0.f) * saW[e];
        __syncthreads();
        for (int off = 128; off; off >>= 1) {
            if (e < off) red[e] += red[e + off];
            __syncthreads();
        }
        if (e == 0) cmol[b] = red[0];
    }
}

// Sequence attention: softmax over S, seq_ctx[b] = elu(sum_s w_s * tf[b,s,:])
__global__ __launch_bounds__(512) void seqattn_kernel(
    const float* __restrict__ act, const float* __restrict__ mask,
    const float* __restrict__ saW, const float* __restrict__ saB,
    const float* __restrict__ cmol, const float* __restrict__ tf,
    float* __restrict__ seqctx)
{
    const int b   = blockIdx.x;
    const int tid = threadIdx.x;
    __shared__ float w_s[SEQ];
    __shared__ float red[SEQ];
    const float* arow = &act[((size_t)b*SEQ + tid)*EMB];
    const float* w2 = &saW[EMB];
    float ad = 0.f;
    for (int e = 0; e < EMB; e += 4) {
        float4 a = *reinterpret_cast<const float4*>(&arow[e]);
        float4 w = *reinterpret_cast<const float4*>(&w2[e]);
        ad += a.x*w.x + a.y*w.y + a.z*w.z + a.w*w.w;
    }
    float mk = mask[b*SEQ + tid];
    float sc = lrelu(cmol[b] + ad + saB[0]) + (mk == 0.f ? NEGV : 0.f);
    red[tid] = sc; __syncthreads();
    for (int off = 256; off; off >>= 1) {
        if (tid < off) red[tid] = fmaxf(red[tid], red[tid + off]);
        __syncthreads();
    }
    float m = red[0]; __syncthreads();
    float ev = expf(sc - m);
    red[tid] = ev; __syncthreads();
    for (int off = 256; off; off >>= 1) {
        if (tid < off) red[tid] += red[tid + off];
        __syncthreads();
    }
    float inv = 1.f / red[0];
    w_s[tid] = ev * inv * mk;
    __syncthreads();
    // PV: 2 s-slices per e, combined via LDS
    const int e = tid & 255, half = tid >> 8;
    float acc = 0.f;
    const int s0 = half << 8;
    for (int s = s0; s < s0 + 256; ++s)
        acc += w_s[s] * tf[((size_t)b*SEQ + s)*EMB + e];
    red[tid] = acc;
    __syncthreads();
    if (half == 0)
        seqctx[(size_t)b*EMB + e] = elu1(red[e] + red[e + 256]);
}

// Y[b][g] = X[b]·Wm[g] + bias[g];  one wave per (b,g). grid (192, 8).
__global__ __launch_bounds__(256) void matvec8_kernel(
    const float* __restrict__ X, const float* __restrict__ Wm,
    const float* __restrict__ bias, float* __restrict__ Y)
{
    const int g    = blockIdx.x * 4 + (threadIdx.x >> 6);
    const int b    = blockIdx.y;
    const int lane = threadIdx.x & 63;
    float4 w = *reinterpret_cast<const float4*>(&Wm[(size_t)g*EMB + (lane << 2)]);
    float4 x = *reinterpret_cast<const float4*>(&X[(size_t)b*EMB + (lane << 2)]);
    float d = w.x*x.x + w.y*x.y + w.z*x.z + w.w*x.w;
    #pragma unroll
    for (int off = 32; off; off >>= 1) d += __shfl_xor(d, off, 64);
    if (lane == 0) Y[(size_t)b*G3 + g] = d + bias[g];
}

// elementwise GRU combine for seq phase; sfin may alias sfout
__global__ __launch_bounds__(256) void seqgru_el_kernel(
    const float* __restrict__ sgi, const float* __restrict__ sgh,
    const float* __restrict__ sfin,
    float* __restrict__ sfout, float* __restrict__ actseq)
{
    const int b = blockIdx.x;
    const int e = threadIdx.x;
    float rg = sigm(sgi[b*G3 + e]       + sgh[b*G3 + e]);
    float z  = sigm(sgi[b*G3 + EMB + e] + sgh[b*G3 + EMB + e]);
    float n  = tanhf(sgi[b*G3 + 2*EMB + e] + rg * sgh[b*G3 + 2*EMB + e]);
    float hp = sfin[b*EMB + e];
    float hv = (1.f - z)*n + z*hp;
    sfout[b*EMB + e]  = hv;
    actseq[b*EMB + e] = fmaxf(hv, 0.f);
}

extern "C" void kernel_launch(void* const* d_in, const int* in_sizes, int n_in,
                              void* d_out, int out_size, void* d_ws, size_t ws_size,
                              hipStream_t stream) {
    (void)in_sizes; (void)n_in; (void)out_size; (void)ws_size;
    const float* amino  = (const float*)d_in[0];
    const float* mask   = (const float*)d_in[1];
    const float* embW   = (const float*)d_in[2];
    const float* embB   = (const float*)d_in[3];
    const float* nbW    = (const float*)d_in[4];
    const float* nbB    = (const float*)d_in[5];
    const float* alignW = (const float*)d_in[6];
    const float* alignB = (const float*)d_in[7];
    const float* attW   = (const float*)d_in[8];
    const float* attB   = (const float*)d_in[9];
    const float* gwih   = (const float*)d_in[10];
    const float* gwhh   = (const float*)d_in[11];
    const float* gbih   = (const float*)d_in[12];
    const float* gbhh   = (const float*)d_in[13];
    const float* saW    = (const float*)d_in[14];
    const float* saB    = (const float*)d_in[15];
    const float* satW   = (const float*)d_in[16];
    const float* satB   = (const float*)d_in[17];
    const float* sgwih  = (const float*)d_in[18];
    const float* sgbih  = (const float*)d_in[19];
    const float* sgwhh  = (const float*)d_in[20];
    const float* sgbhh  = (const float*)d_in[21];
    const int*   idx    = (const int*)d_in[22];

    char* cur = (char*)d_ws;
    auto alloc = [&](size_t bytes) -> char* {
        char* p = cur; cur += (bytes + 255) & ~(size_t)255; return p;
    };
    float* feat    = (float*)alloc((size_t)BS*EMB*4);
    float* nbase   = (float*)alloc((size_t)BS*EMB*4);
    float* h       = (float*)alloc((size_t)BS*EMB*4);
    float* gi      = (float*)alloc((size_t)BS*G3*4);
    float* gh      = (float*)alloc((size_t)BS*G3*4);
    float* cdot    = (float*)alloc(BS*4);
    float* ndot    = (float*)alloc(BS*4);
    float* seqfeat = (float*)alloc(BSZ*EMB*4);
    float* cmol    = (float*)alloc(64*4);
    float* seqctx  = (float*)alloc(BSZ*EMB*4);
    float* sgi     = (float*)alloc(BSZ*G3*4);
    float* sgh     = (float*)alloc(BSZ*G3*4);
    ushort* featbf  = (ushort*)alloc((size_t)BS*EMB*2);
    ushort* nbasebf = (ushort*)alloc((size_t)BS*EMB*2);
    ushort* actbf   = (ushort*)alloc((size_t)BS*EMB*2);
    ushort* hbf     = (ushort*)alloc((size_t)BS*EMB*2);
    ushort* ctxbf   = (ushort*)alloc((size_t)BS*EMB*2);
    ushort* ntb     = (ushort*)alloc((size_t)BS*EMB*2);
    ushort* embWbf  = (ushort*)alloc((size_t)EMB*INITD*2);
    ushort* nbWbf   = (ushort*)alloc((size_t)EMB*INITD*2);
    ushort* attWbf  = (ushort*)alloc((size_t)3*EMB*EMB*2);
    ushort* gwihbf  = (ushort*)alloc((size_t)3*G3*EMB*2);
    ushort* gwhhbf  = (ushort*)alloc((size_t)3*G3*EMB*2);
    ushort* satWbf  = (ushort*)alloc((size_t)EMB*EMB*2);
    ushort* aminobf = (ushort*)gi;     // alias: gi first written after aminobf dead
    float*  tf      = gi;              // alias: seq phase after GRU rounds

    float* out    = (float*)d_out;
    float* actseq = out;               // (B,E)
    float* act    = out + BSZ*EMB;     // (B,S,E)

    convert7_kernel<<<dim3(1024, 7), 256, 0, stream>>>(
        amino, aminobf, BS*INITD,
        embW,  embWbf,  EMB*INITD,
        nbW,   nbWbf,   EMB*INITD,
        attW,  attWbf,  3*EMB*EMB,
        gwih,  gwihbf,  3*G3*EMB,
        gwhh,  gwhhbf,  3*G3*EMB,
        satW,  satWbf,  EMB*EMB);

    featnbase_kernel<<<512, 256, 0, stream>>>(
        aminobf, embWbf, embB, feat, featbf, nbWbf, nbB, nbase, nbasebf);

    for (int d = 0; d < 3; ++d) {
        const float*  center   = (d == 0) ? feat    : act;
        const float*  nbrbase  = (d == 0) ? nbase   : act;
        const ushort* nbrbf    = (d == 0) ? nbasebf : actbf;
        const float*  hprev    = (d == 0) ? feat    : h;
        const ushort* hprevbf  = (d == 0) ? featbf  : hbf;
        round_pre_kernel<<<1280, 256, 0, stream>>>(
            nbrbf, attWbf + (size_t)d*EMB*EMB, attB + d*EMB, ntb,
            hprevbf, gwhhbf + (size_t)d*G3*EMB, gbhh + d*G3, gh,
            center, nbrbase, alignW + d*2*EMB, cdot, ndot);
        attn_kernel<<<BS, 256, 0, stream>>>(cdot, ndot, idx, ntb, alignB + d, ctxbf);
        gemm_mfma<0,true,false><<<dim3(64, 12), 256, 0, stream>>>(
            ctxbf, gwihbf + (size_t)d*G3*EMB, gbih + d*G3, gi, nullptr, G3, EMB);
        gru_kernel<<<BS, 256, 0, stream>>>(gi, gh, hprev, h, hbf, act, actbf);
    }

    // sequence phase (scores/ctx invariant across T=2 -> compute once)
    seqpre_kernel<<<264, 256, 0, stream>>>(
        actbf, satWbf, satB, tf, act, mask, saW, seqfeat, cmol);
    seqattn_kernel<<<BSZ, 512, 0, stream>>>(act, mask, saW, saB, cmol, tf, seqctx);
    matvec8_kernel<<<dim3(G3/4, BSZ), 256, 0, stream>>>(seqctx, sgwih, sgbih, sgi);
    for (int t = 0; t < 2; ++t) {
        matvec8_kernel<<<dim3(G3/4, BSZ), 256, 0, stream>>>(seqfeat, sgwhh, sgbhh, sgh);
        seqgru_el_kernel<<<BSZ, 256, 0, stream>>>(sgi, sgh, seqfeat, seqfeat, actseq);
    }
}

// Round 4
// 184.187 us; speedup vs baseline: 1.4244x; 1.4244x over previous
//
#include <hip/hip_runtime.h>
#include <math.h>

// ProGAT: B=8,S=512,NB=23,INIT=512,E=256,R=3,T=2
// R4: sequence tail parallelized (seqscore folded in seqpre; seqsoftmax/
// seqpv/seqfinish grid-wide); float4 GRU. MFMA GEMMs double-buffered 64x64.

#define BSZ   8
#define SEQ   512
#define NBR   23
#define EMB   256
#define INITD 512
#define BS    (BSZ*SEQ)     // 4096
#define G3    (3*EMB)       // 768
#define NEGV  -9e8f

typedef __attribute__((ext_vector_type(8))) short short8;
typedef __attribute__((ext_vector_type(4))) float f32x4;

__device__ __forceinline__ float lrelu(float x){ return x > 0.f ? x : 0.01f*x; }
__device__ __forceinline__ float elu1 (float x){ return x > 0.f ? x : (expf(x)-1.f); }
__device__ __forceinline__ float sigm (float x){ return 1.f/(1.f+expf(-x)); }
__device__ __forceinline__ float bf2f(ushort u){
    union { unsigned int i; float f; } v; v.i = ((unsigned int)u) << 16; return v.f;
}
__device__ __forceinline__ ushort f2bf(float f){
    union { float f; unsigned int i; } v; v.f = f;
    unsigned int u = v.i;
    return (ushort)((u + 0x7FFFu + ((u >> 16) & 1u)) >> 16);   // RNE
}

struct GemmLds { ushort A[2][64][64]; ushort W[2][64][64]; };  // 32 KiB

// ---- fp32 -> bf16 converter, 7 segments in one dispatch (blockIdx.y = seg)
__global__ __launch_bounds__(256) void convert7_kernel(
    const float* s0, ushort* d0, int n0,
    const float* s1, ushort* d1, int n1,
    const float* s2, ushort* d2, int n2,
    const float* s3, ushort* d3, int n3,
    const float* s4, ushort* d4, int n4,
    const float* s5, ushort* d5, int n5,
    const float* s6, ushort* d6, int n6)
{
    const float* srcs[7] = {s0,s1,s2,s3,s4,s5,s6};
    ushort* dsts[7] = {d0,d1,d2,d3,d4,d5,d6};
    int ns[7] = {n0,n1,n2,n3,n4,n5,n6};
    int seg = blockIdx.y;
    const float* s = srcs[seg]; ushort* d = dsts[seg]; int n = ns[seg];
    size_t i = ((size_t)blockIdx.x * 256 + threadIdx.x) * 8;
    size_t stride = (size_t)gridDim.x * 256 * 8;
    for (; i < (size_t)n; i += stride) {
        float4 a = *reinterpret_cast<const float4*>(s + i);
        float4 b = *reinterpret_cast<const float4*>(s + i + 4);
        uint4 o;
        o.x = (unsigned)f2bf(a.x) | ((unsigned)f2bf(a.y) << 16);
        o.y = (unsigned)f2bf(a.z) | ((unsigned)f2bf(a.w) << 16);
        o.z = (unsigned)f2bf(b.x) | ((unsigned)f2bf(b.y) << 16);
        o.w = (unsigned)f2bf(b.z) | ((unsigned)f2bf(b.w) << 16);
        *reinterpret_cast<uint4*>(d + i) = o;
    }
}

// ---- C = act(A @ W^T + bias); MFMA 16x16x32 bf16, 64x64 tile, 4 waves,
// BK=64 double-buffered.
template<int ACT, bool WF32, bool WBF>
__device__ __forceinline__ void gemm_dev(
    const ushort* __restrict__ A, const ushort* __restrict__ W,
    const float* __restrict__ bias,
    float* __restrict__ C, ushort* __restrict__ Cbf,
    int N, int K, int bx, int by, GemmLds& L)
{
    const int tid = threadIdx.x;
    const int m0 = bx * 64, n0 = by * 64;
    const int wv = tid >> 6, lane = tid & 63;
    const int fr = lane & 15, grp = lane >> 4;
    const int lrow = tid >> 3, lc8 = tid & 7;   // staging: 8 lanes/row, 128B/row
    const int kc = K >> 3;                       // row stride in 16B chunks
    const int sw = lc8 ^ (lrow & 7);             // XOR bank swizzle (T2)

    f32x4 acc[4];
    #pragma unroll
    for (int c = 0; c < 4; ++c) acc[c] = (f32x4){0.f, 0.f, 0.f, 0.f};

    const float4* A4 = reinterpret_cast<const float4*>(A);
    const float4* W4 = reinterpret_cast<const float4*>(W);

    float4 a0 = A4[(size_t)(m0 + lrow)      * kc + lc8];
    float4 a1 = A4[(size_t)(m0 + lrow + 32) * kc + lc8];
    float4 w0 = W4[(size_t)(n0 + lrow)      * kc + lc8];
    float4 w1 = W4[(size_t)(n0 + lrow + 32) * kc + lc8];
    *reinterpret_cast<float4*>(&L.A[0][lrow     ][sw << 3]) = a0;
    *reinterpret_cast<float4*>(&L.A[0][lrow + 32][sw << 3]) = a1;
    *reinterpret_cast<float4*>(&L.W[0][lrow     ][sw << 3]) = w0;
    *reinterpret_cast<float4*>(&L.W[0][lrow + 32][sw << 3]) = w1;
    __syncthreads();

    const int ar = (wv << 4) + fr;
    int cur = 0;
    for (int k0 = 64; k0 < K; k0 += 64) {
        a0 = A4[(size_t)(m0 + lrow)      * kc + (k0 >> 3) + lc8];
        a1 = A4[(size_t)(m0 + lrow + 32) * kc + (k0 >> 3) + lc8];
        w0 = W4[(size_t)(n0 + lrow)      * kc + (k0 >> 3) + lc8];
        w1 = W4[(size_t)(n0 + lrow + 32) * kc + (k0 >> 3) + lc8];
        #pragma unroll
        for (int ks = 0; ks < 2; ++ks) {
            short8 af = *reinterpret_cast<const short8*>(
                &L.A[cur][ar][((((ks << 2) + grp) ^ (ar & 7)) << 3)]);
            #pragma unroll
            for (int c = 0; c < 4; ++c) {
                const int br = (c << 4) + fr;
                short8 bv = *reinterpret_cast<const short8*>(
                    &L.W[cur][br][((((ks << 2) + grp) ^ (br & 7)) << 3)]);
                acc[c] = __builtin_amdgcn_mfma_f32_16x16x32_bf16(af, bv, acc[c], 0, 0, 0);
            }
        }
        *reinterpret_cast<float4*>(&L.A[cur^1][lrow     ][sw << 3]) = a0;
        *reinterpret_cast<float4*>(&L.A[cur^1][lrow + 32][sw << 3]) = a1;
        *reinterpret_cast<float4*>(&L.W[cur^1][lrow     ][sw << 3]) = w0;
        *reinterpret_cast<float4*>(&L.W[cur^1][lrow + 32][sw << 3]) = w1;
        __syncthreads();
        cur ^= 1;
    }
    #pragma unroll
    for (int ks = 0; ks < 2; ++ks) {
        short8 af = *reinterpret_cast<const short8*>(
            &L.A[cur][ar][((((ks << 2) + grp) ^ (ar & 7)) << 3)]);
        #pragma unroll
        for (int c = 0; c < 4; ++c) {
            const int br = (c << 4) + fr;
            short8 bv = *reinterpret_cast<const short8*>(
                &L.W[cur][br][((((ks << 2) + grp) ^ (br & 7)) << 3)]);
            acc[c] = __builtin_amdgcn_mfma_f32_16x16x32_bf16(af, bv, acc[c], 0, 0, 0);
        }
    }

    // D layout (m89-verified): col = lane&15, row = (lane>>4)*4 + j
    const int mrow = m0 + (wv << 4) + (grp << 2);
    #pragma unroll
    for (int c = 0; c < 4; ++c) {
        const int n = n0 + (c << 4) + fr;
        const float bv = bias[n];
        #pragma unroll
        for (int j = 0; j < 4; ++j) {
            float t = acc[c][j] + bv;
            if (ACT == 1) t = lrelu(t);
            size_t off = (size_t)(mrow + j) * N + n;
            if (WF32) C[off] = t;
            if (WBF)  Cbf[off] = f2bf(t);
        }
    }
}

template<int ACT, bool WF32, bool WBF>
__global__ __launch_bounds__(256) void gemm_mfma(
    const ushort* __restrict__ A, const ushort* __restrict__ W,
    const float* __restrict__ bias,
    float* __restrict__ C, ushort* __restrict__ Cbf, int N, int K)
{
    __shared__ GemmLds L;
    gemm_dev<ACT,WF32,WBF>(A, W, bias, C, Cbf, N, K, blockIdx.x, blockIdx.y, L);
}

// ---- fat: feat GEMM (blocks 0..255) + nbase GEMM (256..511), K=512
__global__ __launch_bounds__(256) void featnbase_kernel(
    const ushort* __restrict__ aminobf,
    const ushort* __restrict__ embWbf, const float* __restrict__ embB,
    float* __restrict__ feat, ushort* __restrict__ featbf,
    const ushort* __restrict__ nbWbf, const float* __restrict__ nbB,
    float* __restrict__ nbase, ushort* __restrict__ nbasebf)
{
    __shared__ GemmLds L;
    int blk = blockIdx.x;
    if (blk < 256)
        gemm_dev<1,true,true>(aminobf, embWbf, embB, feat, featbf, EMB, INITD, blk & 63, blk >> 6, L);
    else {
        blk -= 256;
        gemm_dev<1,true,true>(aminobf, nbWbf, nbB, nbase, nbasebf, EMB, INITD, blk & 63, blk >> 6, L);
    }
}

// ---- fat per round: nt GEMM (0..255) + gh GEMM (256..1023) + dot2 (1024..1279)
__global__ __launch_bounds__(256) void round_pre_kernel(
    const ushort* __restrict__ nbrbf, const ushort* __restrict__ attWd,
    const float* __restrict__ attBd, ushort* __restrict__ ntb,
    const ushort* __restrict__ hprevbf, const ushort* __restrict__ gwhhd,
    const float* __restrict__ gbhhd, float* __restrict__ gh,
    const float* __restrict__ center, const float* __restrict__ nbrbase,
    const float* __restrict__ alignWd,
    float* __restrict__ cdot, float* __restrict__ ndot)
{
    __shared__ GemmLds L;
    int blk = blockIdx.x;
    if (blk < 256) {
        gemm_dev<0,false,true>(nbrbf, attWd, attBd, nullptr, ntb, EMB, EMB, blk & 63, blk >> 6, L);
    } else if (blk < 1024) {
        int b = blk - 256;
        gemm_dev<0,true,false>(hprevbf, gwhhd, gbhhd, gh, nullptr, G3, EMB, b & 63, b >> 6, L);
    } else {
        const int b    = blk - 1024;
        const int lane = threadIdx.x & 63;
        const int wv   = threadIdx.x >> 6;
        const int e    = lane << 2;
        const int rb   = b * 16 + wv * 4;
        float4 w0 = *reinterpret_cast<const float4*>(&alignWd[e]);
        float4 w1 = *reinterpret_cast<const float4*>(&alignWd[EMB + e]);
        #pragma unroll
        for (int i = 0; i < 4; ++i) {
            const int r = rb + i;
            float4 xc = *reinterpret_cast<const float4*>(&center[(size_t)r*EMB + e]);
            float4 xn = *reinterpret_cast<const float4*>(&nbrbase[(size_t)r*EMB + e]);
            float ac = xc.x*w0.x + xc.y*w0.y + xc.z*w0.z + xc.w*w0.w;
            float an = xn.x*w1.x + xn.y*w1.y + xn.z*w1.z + xn.w*w1.w;
            #pragma unroll
            for (int off = 32; off; off >>= 1) {
                ac += __shfl_xor(ac, off, 64);
                an += __shfl_xor(an, off, 64);
            }
            if (lane == 0) { cdot[r] = ac; ndot[r] = an; }
        }
    }
}

// Per row r: neighbor softmax over NB, ctxbf[r] = bf16(elu(sum_n w_n * nt[row_n])).
__global__ __launch_bounds__(256) void attn_kernel(
    const float* __restrict__ cdot, const float* __restrict__ ndot,
    const int* __restrict__ idx, const ushort* __restrict__ nt,
    const float* __restrict__ alignB, ushort* __restrict__ ctxbf)
{
    const int r   = blockIdx.x;
    const int b   = r >> 9;
    const int tid = threadIdx.x;
    __shared__ float w_s[NBR];
    __shared__ float vm_s[NBR];
    __shared__ int   row_s[NBR];
    __shared__ float red[2];
    if (tid < NBR) {
        int j = idx[(size_t)r*NBR + tid];
        int valid = (j >= 0);
        int jj = valid ? j : j + SEQ;       // JAX wrap: f[-1] = last row
        int row = b*SEQ + jj;
        row_s[tid] = row;
        vm_s[tid]  = (float)valid;
        float sc = lrelu(cdot[r] + ndot[row] + alignB[0]);
        w_s[tid] = sc + (valid ? 0.f : NEGV);
    }
    __syncthreads();
    if (tid == 0) {
        float m = w_s[0];
        for (int n = 1; n < NBR; ++n) m = fmaxf(m, w_s[n]);
        red[0] = m;
    }
    __syncthreads();
    if (tid < NBR) w_s[tid] = expf(w_s[tid] - red[0]);
    __syncthreads();
    if (tid == 0) {
        float s = 0.f;
        for (int n = 0; n < NBR; ++n) s += w_s[n];
        red[1] = 1.f / s;
    }
    __syncthreads();
    if (tid < NBR) w_s[tid] *= red[1] * vm_s[tid];
    __syncthreads();
    float acc = 0.f;
    #pragma unroll 1
    for (int n = 0; n < NBR; ++n)
        acc += w_s[n] * bf2f(nt[(size_t)row_s[n]*EMB + tid]);
    ctxbf[(size_t)r*EMB + tid] = f2bf(elu1(acc));
}

// h' = GRU(gi, gh, hprev); float4: 4 rows/block, 64 lanes x 4 elems per row.
__global__ __launch_bounds__(256) void gru_kernel(
    const float* __restrict__ gi, const float* __restrict__ gh,
    const float* __restrict__ hprev,
    float* __restrict__ hout, ushort* __restrict__ hbf,
    float* __restrict__ actout, ushort* __restrict__ actbf)
{
    const size_t r = blockIdx.x * 4 + (threadIdx.x >> 6);
    const int    e = (threadIdx.x & 63) << 2;
    const size_t gb = r*G3 + e, hb = r*EMB + e;
    float4 ir4 = *reinterpret_cast<const float4*>(&gi[gb]);
    float4 iz4 = *reinterpret_cast<const float4*>(&gi[gb + EMB]);
    float4 in4 = *reinterpret_cast<const float4*>(&gi[gb + 2*EMB]);
    float4 hr4 = *reinterpret_cast<const float4*>(&gh[gb]);
    float4 hz4 = *reinterpret_cast<const float4*>(&gh[gb + EMB]);
    float4 hn4 = *reinterpret_cast<const float4*>(&gh[gb + 2*EMB]);
    float4 hp4 = *reinterpret_cast<const float4*>(&hprev[hb]);
    float hv[4], av[4];
    const float ir_[4] = {ir4.x,ir4.y,ir4.z,ir4.w}, iz_[4] = {iz4.x,iz4.y,iz4.z,iz4.w},
                in_[4] = {in4.x,in4.y,in4.z,in4.w}, hr_[4] = {hr4.x,hr4.y,hr4.z,hr4.w},
                hz_[4] = {hz4.x,hz4.y,hz4.z,hz4.w}, hn_[4] = {hn4.x,hn4.y,hn4.z,hn4.w},
                hp_[4] = {hp4.x,hp4.y,hp4.z,hp4.w};
    #pragma unroll
    for (int i = 0; i < 4; ++i) {
        float rg = sigm(ir_[i] + hr_[i]);
        float z  = sigm(iz_[i] + hz_[i]);
        float n  = tanhf(in_[i] + rg*hn_[i]);
        hv[i] = (1.f - z)*n + z*hp_[i];
        av[i] = fmaxf(hv[i], 0.f);
    }
    *reinterpret_cast<float4*>(&hout[hb])   = make_float4(hv[0],hv[1],hv[2],hv[3]);
    *reinterpret_cast<float4*>(&actout[hb]) = make_float4(av[0],av[1],av[2],av[3]);
    uint2 hp, ap;
    hp.x = (unsigned)f2bf(hv[0]) | ((unsigned)f2bf(hv[1]) << 16);
    hp.y = (unsigned)f2bf(hv[2]) | ((unsigned)f2bf(hv[3]) << 16);
    ap.x = (unsigned)f2bf(av[0]) | ((unsigned)f2bf(av[1]) << 16);
    ap.y = (unsigned)f2bf(av[2]) | ((unsigned)f2bf(av[3]) << 16);
    *reinterpret_cast<uint2*>(&hbf[hb])  = hp;
    *reinterpret_cast<uint2*>(&actbf[hb]) = ap;
}

// ---- fat: tf GEMM (0..255) + seqsum (256..263) + seqscore (264..519)
__global__ __launch_bounds__(256) void seqpre_kernel(
    const ushort* __restrict__ actbf, const ushort* __restrict__ satWbf,
    const float* __restrict__ satB, float* __restrict__ tf,
    const float* __restrict__ act, const float* __restrict__ mask,
    const float* __restrict__ saW,
    float* __restrict__ seqfeat, float* __restrict__ cmol,
    float* __restrict__ ad)
{
    __shared__ GemmLds L;
    int blk = blockIdx.x;
    if (blk < 256) {
        gemm_dev<0,true,false>(actbf, satWbf, satB, tf, nullptr, EMB, EMB, blk & 63, blk >> 6, L);
    } else if (blk < 264) {
        const int b = blk - 256;
        const int e = threadIdx.x;
        float acc = 0.f;
        for (int s = 0; s < SEQ; ++s)
            acc += act[((size_t)b*SEQ + s)*EMB + e] * mask[b*SEQ + s];
        seqfeat[b*EMB + e] = acc;
        float* red = reinterpret_cast<float*>(&L);
        red[e] = fmaxf(acc, 0.f) * saW[e];
        __syncthreads();
        for (int off = 128; off; off >>= 1) {
            if (e < off) red[e] += red[e + off];
            __syncthreads();
        }
        if (e == 0) cmol[b] = red[0];
    } else {
        // seqscore: ad[r] = act[r,:]·saW[E:], one wave per row, 16 rows/block
        const int b2   = blk - 264;
        const int lane = threadIdx.x & 63;
        const int wv   = threadIdx.x >> 6;
        const int e    = lane << 2;
        const int rb   = b2 * 16 + wv * 4;
        float4 w1 = *reinterpret_cast<const float4*>(&saW[EMB + e]);
        #pragma unroll
        for (int i = 0; i < 4; ++i) {
            const int r = rb + i;
            float4 xa = *reinterpret_cast<const float4*>(&act[(size_t)r*EMB + e]);
            float an = xa.x*w1.x + xa.y*w1.y + xa.z*w1.z + xa.w*w1.w;
            #pragma unroll
            for (int off = 32; off; off >>= 1) an += __shfl_xor(an, off, 64);
            if (lane == 0) ad[r] = an;
        }
    }
}

// softmax over S per batch: w[b,s] = softmax(lrelu(cmol+ad+saB)+smask)*mask
__global__ __launch_bounds__(512) void seqsoftmax_kernel(
    const float* __restrict__ ad, const float* __restrict__ mask,
    const float* __restrict__ saB, const float* __restrict__ cmol,
    float* __restrict__ wvec)
{
    const int b = blockIdx.x;
    const int s = threadIdx.x;
    __shared__ float red[SEQ];
    float mk = mask[b*SEQ + s];
    float sc = lrelu(cmol[b] + ad[b*SEQ + s] + saB[0]) + (mk == 0.f ? NEGV : 0.f);
    red[s] = sc; __syncthreads();
    for (int off = 256; off; off >>= 1) {
        if (s < off) red[s] = fmaxf(red[s], red[s + off]);
        __syncthreads();
    }
    float m = red[0]; __syncthreads();
    float ev = expf(sc - m);
    red[s] = ev; __syncthreads();
    for (int off = 256; off; off >>= 1) {
        if (s < off) red[s] += red[s + off];
        __syncthreads();
    }
    wvec[b*SEQ + s] = ev / red[0] * mk;
}

// PV partials: block (st,b) accumulates 32 s-rows into partial[b,st,:]
__global__ __launch_bounds__(256) void seqpv_kernel(
    const float* __restrict__ wvec, const float* __restrict__ tf,
    float* __restrict__ partial)
{
    const int st = blockIdx.x, b = blockIdx.y;
    const int e  = threadIdx.x;
    float acc = 0.f;
    const int s0 = st * 32;
    #pragma unroll 4
    for (int s = s0; s < s0 + 32; ++s)
        acc += wvec[b*SEQ + s] * tf[((size_t)b*SEQ + s)*EMB + e];
    partial[((size_t)b*16 + st)*EMB + e] = acc;
}

// combine 16 partials + elu -> seqctx
__global__ __launch_bounds__(256) void seqfinish_kernel(
    const float* __restrict__ partial, float* __restrict__ seqctx)
{
    const int b = blockIdx.x, e = threadIdx.x;
    float acc = 0.f;
    #pragma unroll
    for (int st = 0; st < 16; ++st)
        acc += partial[((size_t)b*16 + st)*EMB + e];
    seqctx[(size_t)b*EMB + e] = elu1(acc);
}

// Y[b][g] = X[b]·Wm[g] + bias[g];  one wave per (b,g). grid (192, 8).
__global__ __launch_bounds__(256) void matvec8_kernel(
    const float* __restrict__ X, const float* __restrict__ Wm,
    const float* __restrict__ bias, float* __restrict__ Y)
{
    const int g    = blockIdx.x * 4 + (threadIdx.x >> 6);
    const int b    = blockIdx.y;
    const int lane = threadIdx.x & 63;
    float4 w = *reinterpret_cast<const float4*>(&Wm[(size_t)g*EMB + (lane << 2)]);
    float4 x = *reinterpret_cast<const float4*>(&X[(size_t)b*EMB + (lane << 2)]);
    float d = w.x*x.x + w.y*x.y + w.z*x.z + w.w*x.w;
    #pragma unroll
    for (int off = 32; off; off >>= 1) d += __shfl_xor(d, off, 64);
    if (lane == 0) Y[(size_t)b*G3 + g] = d + bias[g];
}

// elementwise GRU combine for seq phase; sfin may alias sfout
__global__ __launch_bounds__(256) void seqgru_el_kernel(
    const float* __restrict__ sgi, const float* __restrict__ sgh,
    const float* __restrict__ sfin,
    float* __restrict__ sfout, float* __restrict__ actseq)
{
    const int b = blockIdx.x;
    const int e = threadIdx.x;
    float rg = sigm(sgi[b*G3 + e]       + sgh[b*G3 + e]);
    float z  = sigm(sgi[b*G3 + EMB + e] + sgh[b*G3 + EMB + e]);
    float n  = tanhf(sgi[b*G3 + 2*EMB + e] + rg * sgh[b*G3 + 2*EMB + e]);
    float hp = sfin[b*EMB + e];
    float hv = (1.f - z)*n + z*hp;
    sfout[b*EMB + e]  = hv;
    actseq[b*EMB + e] = fmaxf(hv, 0.f);
}

extern "C" void kernel_launch(void* const* d_in, const int* in_sizes, int n_in,
                              void* d_out, int out_size, void* d_ws, size_t ws_size,
                              hipStream_t stream) {
    (void)in_sizes; (void)n_in; (void)out_size; (void)ws_size;
    const float* amino  = (const float*)d_in[0];
    const float* mask   = (const float*)d_in[1];
    const float* embW   = (const float*)d_in[2];
    const float* embB   = (const float*)d_in[3];
    const float* nbW    = (const float*)d_in[4];
    const float* nbB    = (const float*)d_in[5];
    const float* alignW = (const float*)d_in[6];
    const float* alignB = (const float*)d_in[7];
    const float* attW   = (const float*)d_in[8];
    const float* attB   = (const float*)d_in[9];
    const float* gwih   = (const float*)d_in[10];
    const float* gwhh   = (const float*)d_in[11];
    const float* gbih   = (const float*)d_in[12];
    const float* gbhh   = (const float*)d_in[13];
    const float* saW    = (const float*)d_in[14];
    const float* saB    = (const float*)d_in[15];
    const float* satW   = (const float*)d_in[16];
    const float* satB   = (const float*)d_in[17];
    const float* sgwih  = (const float*)d_in[18];
    const float* sgbih  = (const float*)d_in[19];
    const float* sgwhh  = (const float*)d_in[20];
    const float* sgbhh  = (const float*)d_in[21];
    const int*   idx    = (const int*)d_in[22];

    char* cur = (char*)d_ws;
    auto alloc = [&](size_t bytes) -> char* {
        char* p = cur; cur += (bytes + 255) & ~(size_t)255; return p;
    };
    float* feat    = (float*)alloc((size_t)BS*EMB*4);
    float* nbase   = (float*)alloc((size_t)BS*EMB*4);
    float* h       = (float*)alloc((size_t)BS*EMB*4);
    float* gi      = (float*)alloc((size_t)BS*G3*4);
    float* gh      = (float*)alloc((size_t)BS*G3*4);
    float* cdot    = (float*)alloc(BS*4);
    float* ndot    = (float*)alloc(BS*4);
    float* seqfeat = (float*)alloc(BSZ*EMB*4);
    float* cmol    = (float*)alloc(64*4);
    float* seqctx  = (float*)alloc(BSZ*EMB*4);
    float* sgi     = (float*)alloc(BSZ*G3*4);
    float* sgh     = (float*)alloc(BSZ*G3*4);
    float* partial = (float*)alloc((size_t)BSZ*16*EMB*4);
    ushort* featbf  = (ushort*)alloc((size_t)BS*EMB*2);
    ushort* nbasebf = (ushort*)alloc((size_t)BS*EMB*2);
    ushort* actbf   = (ushort*)alloc((size_t)BS*EMB*2);
    ushort* hbf     = (ushort*)alloc((size_t)BS*EMB*2);
    ushort* ctxbf   = (ushort*)alloc((size_t)BS*EMB*2);
    ushort* ntb     = (ushort*)alloc((size_t)BS*EMB*2);
    ushort* embWbf  = (ushort*)alloc((size_t)EMB*INITD*2);
    ushort* nbWbf   = (ushort*)alloc((size_t)EMB*INITD*2);
    ushort* attWbf  = (ushort*)alloc((size_t)3*EMB*EMB*2);
    ushort* gwihbf  = (ushort*)alloc((size_t)3*G3*EMB*2);
    ushort* gwhhbf  = (ushort*)alloc((size_t)3*G3*EMB*2);
    ushort* satWbf  = (ushort*)alloc((size_t)EMB*EMB*2);
    ushort* aminobf = (ushort*)gi;     // alias: gi first written after aminobf dead
    float*  tf      = gi;              // alias: seq phase after GRU rounds
    float*  ad      = cdot;            // alias: rounds done
    float*  wvec    = ndot;            // alias: rounds done

    float* out    = (float*)d_out;
    float* actseq = out;               // (B,E)
    float* act    = out + BSZ*EMB;     // (B,S,E)

    convert7_kernel<<<dim3(1024, 7), 256, 0, stream>>>(
        amino, aminobf, BS*INITD,
        embW,  embWbf,  EMB*INITD,
        nbW,   nbWbf,   EMB*INITD,
        attW,  attWbf,  3*EMB*EMB,
        gwih,  gwihbf,  3*G3*EMB,
        gwhh,  gwhhbf,  3*G3*EMB,
        satW,  satWbf,  EMB*EMB);

    featnbase_kernel<<<512, 256, 0, stream>>>(
        aminobf, embWbf, embB, feat, featbf, nbWbf, nbB, nbase, nbasebf);

    for (int d = 0; d < 3; ++d) {
        const float*  center   = (d == 0) ? feat    : act;
        const float*  nbrbase  = (d == 0) ? nbase   : act;
        const ushort* nbrbf    = (d == 0) ? nbasebf : actbf;
        const float*  hprev    = (d == 0) ? feat    : h;
        const ushort* hprevbf  = (d == 0) ? featbf  : hbf;
        round_pre_kernel<<<1280, 256, 0, stream>>>(
            nbrbf, attWbf + (size_t)d*EMB*EMB, attB + d*EMB, ntb,
            hprevbf, gwhhbf + (size_t)d*G3*EMB, gbhh + d*G3, gh,
            center, nbrbase, alignW + d*2*EMB, cdot, ndot);
        attn_kernel<<<BS, 256, 0, stream>>>(cdot, ndot, idx, ntb, alignB + d, ctxbf);
        gemm_mfma<0,true,false><<<dim3(64, 12), 256, 0, stream>>>(
            ctxbf, gwihbf + (size_t)d*G3*EMB, gbih + d*G3, gi, nullptr, G3, EMB);
        gru_kernel<<<BS/4, 256, 0, stream>>>(gi, gh, hprev, h, hbf, act, actbf);
    }

    // sequence phase (scores/ctx invariant across T=2 -> compute once)
    seqpre_kernel<<<520, 256, 0, stream>>>(
        actbf, satWbf, satB, tf, act, mask, saW, seqfeat, cmol, ad);
    seqsoftmax_kernel<<<BSZ, 512, 0, stream>>>(ad, mask, saB, cmol, wvec);
    seqpv_kernel<<<dim3(16, BSZ), 256, 0, stream>>>(wvec, tf, partial);
    seqfinish_kernel<<<BSZ, 256, 0, stream>>>(partial, seqctx);
    matvec8_kernel<<<dim3(G3/4, BSZ), 256, 0, stream>>>(seqctx, sgwih, sgbih, sgi);
    for (int t = 0; t < 2; ++t) {
        matvec8_kernel<<<dim3(G3/4, BSZ), 256, 0, stream>>>(seqfeat, sgwhh, sgbhh, sgh);
        seqgru_el_kernel<<<BSZ, 256, 0, stream>>>(sgi, sgh, seqfeat, seqfeat, actseq);
    }
}